// Round 1
// baseline (418.778 us; speedup 1.0000x reference)
//
#include <hip/hip_runtime.h>

// CTC batch cost, faithful to K.ctc_batch_cost with input_length=T, label_length=L.
// B=512, T=512, C=256 (blank=255), L=64, S=2L+1=129.
//
// One wave64 per batch element. Lane l owns extended states 2l (blank) and
// 2l+1 (label l); lane 63 also owns state 128 (final blank) in a2.
// Wave-synchronous: the only cross-lane dependency per time step is
// alpha[2l-1] (previous lane's odd state) via one __shfl_up. No barriers,
// so the register-level global-load software pipeline (depth NBUF) is never
// drained by s_barrier's vmcnt(0).

#define NEGF (-1e30f)
#define EPSF (1e-7f)

constexpr int T_ = 512;
constexpr int C_ = 256;
constexpr int L_ = 64;
constexpr int NBUF = 16;   // prefetch depth (2*NBUF outstanding loads/wave)

__device__ __forceinline__ float lae2(float a, float b) {
    float m = fmaxf(a, b);
    float d = fminf(a, b) - m;           // <= 0
    return m + __logf(1.0f + __expf(d));
}

__global__ __launch_bounds__(64, 1)
void ctc_kernel(const int* __restrict__ y_true,
                const float* __restrict__ y_pred,
                float* __restrict__ out) {
    const int b    = blockIdx.x;
    const int lane = threadIdx.x;        // 0..63
    const int blank = C_ - 1;

    // labels for this batch row
    const int* lab = y_true + b * L_;
    const int e1    = lab[lane];                         // state 2l+1 class
    const int eprev = (lane == 0) ? blank : lab[lane - 1];
    const bool skip1 = (e1 != blank) && (e1 != eprev);   // skip into state 2l+1

    const float* row = y_pred + (size_t)b * T_ * C_;

    // software-pipelined probability prefetch (registers)
    float pb[NBUF];   // blank prob at step t
    float pl[NBUF];   // label prob at step t
#pragma unroll
    for (int j = 0; j < NBUF; ++j) {
        pb[j] = row[j * C_ + blank];
        pl[j] = row[j * C_ + e1];
    }

    float a0 = NEGF;   // alpha[2l]
    float a1 = NEGF;   // alpha[2l+1]
    float a2 = NEGF;   // alpha[128] (meaningful on lane 63 only)

    for (int t0 = 0; t0 < T_; t0 += NBUF) {
#pragma unroll
        for (int j = 0; j < NBUF; ++j) {
            const int t = t0 + j;
            const float lp0 = __logf(pb[j] + EPSF);
            const float lp1 = __logf(pl[j] + EPSF);

            // issue prefetch for t + NBUF (clamped to stay in-bounds)
            int tn = t + NBUF;
            if (tn > T_ - 1) tn = T_ - 1;
            pb[j] = row[tn * C_ + blank];
            pl[j] = row[tn * C_ + e1];

            if (t == 0) {
                // alpha0: only states 0 and 1 reachable
                a0 = (lane == 0) ? lp0 : NEGF;
                a1 = (lane == 0) ? lp1 : NEGF;
                a2 = NEGF;
            } else {
                float pa1 = __shfl_up(a1, 1, 64);        // alpha[2l-1]
                if (lane == 0) pa1 = NEGF;

                // state 2l (blank): from alpha[2l], alpha[2l-1]
                const float na0 = lae2(a0, pa1) + lp0;

                // state 2l+1: from alpha[2l+1], alpha[2l], (skip) alpha[2l-1]
                const float c3 = skip1 ? pa1 : NEGF;
                const float m  = fmaxf(fmaxf(a1, a0), c3);
                const float s  = __expf(a1 - m) + __expf(a0 - m) + __expf(c3 - m);
                const float na1 = m + __logf(s) + lp1;

                // state 128 (blank): from alpha[128], alpha[127]=own a1
                const float na2 = lae2(a2, a1) + lp0;

                a0 = na0; a1 = na1; a2 = na2;
            }
        }
    }

    if (lane == 63) {
        out[b] = -lae2(a1, a2);          // -logaddexp(alpha[S-1], alpha[S-2])
    }
}

extern "C" void kernel_launch(void* const* d_in, const int* in_sizes, int n_in,
                              void* d_out, int out_size, void* d_ws, size_t ws_size,
                              hipStream_t stream) {
    const int*   y_true = (const int*)d_in[0];
    const float* y_pred = (const float*)d_in[1];
    float*       out    = (float*)d_out;

    const int B = in_sizes[0] / L_;      // 512
    ctc_kernel<<<dim3(B), dim3(64), 0, stream>>>(y_true, y_pred, out);
}

// Round 2
// 402.120 us; speedup vs baseline: 1.0414x; 1.0414x over previous
//
#include <hip/hip_runtime.h>

// CTC batch cost (K.ctc_batch_cost semantics), B=512, T=512, C=256, L=64.
// One wave64 per batch element; lane l owns extended states 2l, 2l+1 (+128 on lane 63).
//
// R2 structure:
//  - y_pred rows staged through a 64KB LDS ring (64 rows x 1KB) with
//    __builtin_amdgcn_global_load_lds (coalesced 16B/lane), chunk c+3 issued
//    at the start of chunk c, hand-placed s_waitcnt vmcnt(N) at chunk
//    boundaries. Compiler cannot sink these -> HBM latency fully hidden.
//  - per-step probabilities ds_read from LDS with PD=8 register lookahead.
//  - cross-lane alpha[2l-1] via DPP wave_shr:1 (VALU latency) instead of
//    ds_permute-based __shfl_up.
//  - no __syncthreads anywhere (1 wave per block).

#define NEGF (-1e30f)
#define EPSF (1e-7f)

constexpr int T_   = 512;
constexpr int C_   = 256;
constexpr int L_   = 64;
constexpr int TCH  = 16;          // time steps per staged chunk
constexpr int NCH  = T_ / TCH;    // 32 chunks
constexpr int NROW = 64;          // LDS ring rows (4 chunks resident)
constexpr int PD   = 8;           // LDS->register prefetch distance (steps)

__device__ __forceinline__ float lae2(float a, float b) {
    float m = fmaxf(a, b);
    float d = fminf(a, b) - m;              // <= 0 (or 0 when both NEG)
    return m + __logf(1.0f + __expf(d));
}

// lane n receives lane n-1's value; lane 0 gets 0.0f (caller overrides).
__device__ __forceinline__ float wave_shr1(float x) {
    int r = __builtin_amdgcn_update_dpp(0, __float_as_int(x),
                                        0x138 /* wave_shr:1 */,
                                        0xF, 0xF, true /* bound_ctrl */);
    return __int_as_float(r);
}

typedef const __attribute__((address_space(1))) void GV;
typedef __attribute__((address_space(3))) void LV;

__global__ __launch_bounds__(64, 1)
void ctc_kernel(const int* __restrict__ y_true,
                const float* __restrict__ y_pred,
                float* __restrict__ out) {
    __shared__ float tile[NROW * C_];       // 64 KB ring: row = t % 64

    const int b     = blockIdx.x;
    const int lane  = threadIdx.x;          // 0..63
    const int blank = C_ - 1;

    const int* lab  = y_true + b * L_;
    const int e1    = lab[lane];            // class of state 2l+1
    const int eprev = (lane == 0) ? blank : lab[lane - 1];
    const bool skip1 = (e1 != blank) && (e1 != eprev);

    const float* __restrict__ row = y_pred + (size_t)b * T_ * C_;

    // ---- stage chunk c (16 rows x 1KB) into the LDS ring, 16 instrs ----
    auto issue_chunk = [&](int c) {
        const float* src = row + (size_t)c * TCH * C_ + lane * 4; // 16B/lane
        float* dst = &tile[((c * TCH) & (NROW - 1)) * C_];
#pragma unroll
        for (int r = 0; r < TCH; ++r) {
            __builtin_amdgcn_global_load_lds((GV*)(src + r * C_),
                                             (LV*)(dst + r * C_),
                                             16, 0, 0);
        }
    };

    issue_chunk(0); issue_chunk(1); issue_chunk(2); issue_chunk(3);
    __builtin_amdgcn_s_waitcnt(0x8F70);     // vmcnt(32): chunks 0,1 resident

    // ---- register lookahead of log-probs for steps 0..PD-1 (chunk 0) ----
    float plp0[PD], plp1[PD];
#pragma unroll
    for (int j = 0; j < PD; ++j) {
        float p0 = tile[j * C_ + blank];    // broadcast ds_read
        float p1 = tile[j * C_ + e1];       // gather ds_read
        plp0[j] = __logf(p0 + EPSF);
        plp1[j] = __logf(p1 + EPSF);
    }

    float a0 = NEGF, a1 = NEGF, a2 = NEGF;

    for (int c = 0; c < NCH; ++c) {
        if (c > 0) {
            const int cn = c + 3;
            if (cn < NCH) {
                issue_chunk(cn);            // overwrites chunk c-1's rows (consumed)
                __builtin_amdgcn_s_waitcnt(0x8F70);  // vmcnt(32): <= c+1 done
            } else if (c + 2 < NCH) {
                __builtin_amdgcn_s_waitcnt(0x4F70);  // vmcnt(16): <= c+1 done
            } else {
                __builtin_amdgcn_s_waitcnt(0x0F70);  // vmcnt(0)
            }
        }
#pragma unroll
        for (int j = 0; j < TCH; ++j) {
            const int t = c * TCH + j;
            const float lp0 = plp0[j & (PD - 1)];
            const float lp1 = plp1[j & (PD - 1)];

            // refill lookahead slot with step t+PD (clamped; chunk <= c+1)
            int tn = t + PD; if (tn > T_ - 1) tn = T_ - 1;
            const int rbase = (tn & (NROW - 1)) * C_;
            const float q0 = tile[rbase + blank];
            const float q1 = tile[rbase + e1];
            plp0[j & (PD - 1)] = __logf(q0 + EPSF);
            plp1[j & (PD - 1)] = __logf(q1 + EPSF);

            if (c == 0 && j == 0) {
                // alpha0: only states 0 (blank) and 1 (first label) reachable
                a0 = (lane == 0) ? lp0 : NEGF;
                a1 = (lane == 0) ? lp1 : NEGF;
                a2 = NEGF;
            } else {
                float pa1 = wave_shr1(a1);          // alpha[2l-1]
                if (lane == 0) pa1 = NEGF;

                // state 2l (blank): from alpha[2l], alpha[2l-1]
                const float na0 = lae2(a0, pa1) + lp0;

                // state 2l+1: from alpha[2l+1], alpha[2l], (skip) alpha[2l-1]
                const float c3 = skip1 ? pa1 : NEGF;
                const float m  = fmaxf(fmaxf(a1, a0), c3);
                const float s  = __expf(a1 - m) + __expf(a0 - m) + __expf(c3 - m);
                const float na1 = m + __logf(s) + lp1;

                // state 128 (blank): from alpha[128], alpha[127] (= own a1)
                const float na2 = lae2(a2, a1) + lp0;

                a0 = na0; a1 = na1; a2 = na2;
            }
        }
    }

    if (lane == 63) {
        out[b] = -lae2(a1, a2);             // -logaddexp(alpha[S-1], alpha[S-2])
    }
}

extern "C" void kernel_launch(void* const* d_in, const int* in_sizes, int n_in,
                              void* d_out, int out_size, void* d_ws, size_t ws_size,
                              hipStream_t stream) {
    const int*   y_true = (const int*)d_in[0];
    const float* y_pred = (const float*)d_in[1];
    float*       out    = (float*)d_out;

    const int B = in_sizes[0] / L_;         // 512
    ctc_kernel<<<dim3(B), dim3(64), 0, stream>>>(y_true, y_pred, out);
}

// Round 3
// 366.819 us; speedup vs baseline: 1.1416x; 1.0962x over previous
//
#include <hip/hip_runtime.h>

// CTC batch cost (K.ctc_batch_cost semantics), B=512, T=512, C=256 (blank=255), L=64.
//
// R3: producer/consumer wave specialization, 4 waves (256 thr) per batch element.
//   wave 0  (consumer): alpha recurrence only. Reads precomputed log-probs from
//            LDS rings. Issues NO global loads -> its vmcnt is always 0, so
//            neither __syncthreads nor the LDS-DMA memory legalizer can ever
//            stall it on memory. Cross-lane alpha[2l-1] via DPP wave_shr:1.
//   waves 1-3 (producers): double-buffered pipeline.
//            stage raw y_pred rows -> LDS via global_load_lds (16B/lane),
//            gather the 65 needed classes, compute log(p+eps), write compact
//            lpL[t][lane] / lpB[t] rings. All HBM latency lives here, covered
//            by the consumer's ~900-cyc chunk time and by 2 waves/SIMD TLP.
// One __syncthreads per 16-step chunk (all 4 waves, equal barrier counts).

#define NEGF (-1e30f)
#define EPSF (1e-7f)

constexpr int T_  = 512;
constexpr int C_  = 256;
constexpr int L_  = 64;
constexpr int TCH = 16;          // time steps per chunk
constexpr int NCH = T_ / TCH;    // 32 chunks

__device__ __forceinline__ float lae2(float a, float b) {
    float m = fmaxf(a, b);
    float d = fminf(a, b) - m;              // <= 0
    return m + __logf(1.0f + __expf(d));
}

// lane n receives lane n-1's value; lane 0 gets 0.0f (caller overrides).
__device__ __forceinline__ float wave_shr1(float x) {
    int r = __builtin_amdgcn_update_dpp(0, __float_as_int(x),
                                        0x138 /* wave_shr:1 */,
                                        0xF, 0xF, true /* bound_ctrl */);
    return __int_as_float(r);
}

typedef const __attribute__((address_space(1))) void GV;
typedef __attribute__((address_space(3))) void LV;

__global__ __launch_bounds__(256, 1)
void ctc_kernel(const int* __restrict__ y_true,
                const float* __restrict__ y_pred,
                float* __restrict__ out) {
    __shared__ float rawb[2][TCH * C_];     // raw y_pred rows, 32 KB
    __shared__ float lpLs[2][TCH][64];      // log p(label_l) per step, 8 KB
    __shared__ float lpBs[2][TCH];          // log p(blank) per step

    const int b     = blockIdx.x;
    const int tid   = threadIdx.x;
    const int lane  = tid & 63;
    const int wid   = tid >> 6;             // 0 = consumer, 1..3 = producers
    const int blank = C_ - 1;

    const float* __restrict__ row = y_pred + (size_t)b * T_ * C_;

    if (wid != 0) {
        // ---------------- producers ----------------
        const int e1 = y_true[b * L_ + lane];     // class gathered by this lane

        // stage chunk c's rows (r % 3 == wid-1) into rawb[buf]
        auto stage = [&](int c, int buf) {
            const float* s = row + (size_t)c * TCH * C_ + lane * 4; // 16 B/lane
            for (int r = wid - 1; r < TCH; r += 3) {
                __builtin_amdgcn_global_load_lds((GV*)(s + r * C_),
                                                 (LV*)(&rawb[buf][r * C_]),
                                                 16, 0, 0);
            }
        };
        // compute log-probs of chunk c from rawb[buf] into lp rings [buf]
        auto produce = [&](int buf) {
            for (int r = wid - 1; r < TCH; r += 3) {
                float pe = rawb[buf][r * C_ + e1];      // gather
                float pb = rawb[buf][r * C_ + blank];   // uniform -> broadcast
                lpLs[buf][r][lane] = __logf(pe + EPSF);
                if (lane == 0) lpBs[buf][r] = __logf(pb + EPSF);
            }
        };

        stage(0, 0);
        stage(1, 1);
        __builtin_amdgcn_s_waitcnt(0x0F70);   // vmcnt(0): chunks 0,1 resident
        produce(0);                            // lp[0] -> ring 0
        __syncthreads();                       // barrier #0

        for (int c = 0; c < NCH; ++c) {
            if (c + 2 < NCH) stage(c + 2, c & 1);      // rawb[c&1] is free now
            if (c + 1 < NCH) produce((c + 1) & 1);     // raw[c+1] drained by
                                                       // this wave's last barrier
            __syncthreads();                   // barrier #c+1
        }
        return;
    }

    // ---------------- consumer (wave 0) ----------------
    const int e1    = y_true[b * L_ + lane];
    const int eprev = (lane == 0) ? blank : y_true[b * L_ + lane - 1];
    const bool skip1 = (e1 != blank) && (e1 != eprev);

    float a0 = NEGF, a1 = NEGF, a2 = NEGF;

    __syncthreads();                           // barrier #0: lp[0] ready

    for (int c = 0; c < NCH; ++c) {
        const int cb = c & 1;

        // hoist the whole chunk's log-probs into registers first
        float l0[TCH], l1[TCH];
#pragma unroll
        for (int j = 0; j < TCH; ++j) {
            l1[j] = lpLs[cb][j][lane];         // stride-1: 2-way bank alias, free
            l0[j] = lpBs[cb][j];               // uniform: broadcast
        }

#pragma unroll
        for (int j = 0; j < TCH; ++j) {
            const float lp0 = l0[j];
            const float lp1 = l1[j];
            if (c == 0 && j == 0) {
                // alpha0: only states 0 (blank) and 1 (first label) reachable
                a0 = (lane == 0) ? lp0 : NEGF;
                a1 = (lane == 0) ? lp1 : NEGF;
                a2 = NEGF;
            } else {
                float pa1 = wave_shr1(a1);     // alpha[2l-1]
                if (lane == 0) pa1 = NEGF;

                // state 2l (blank): from alpha[2l], alpha[2l-1]
                const float na0 = lae2(a0, pa1) + lp0;

                // state 2l+1: from alpha[2l+1], alpha[2l], (skip) alpha[2l-1]
                const float c3 = skip1 ? pa1 : NEGF;
                const float m  = fmaxf(fmaxf(a1, a0), c3);
                const float s  = __expf(a1 - m) + __expf(a0 - m) + __expf(c3 - m);
                const float na1 = m + __logf(s) + lp1;

                // state 128 (blank): from alpha[128], alpha[127] (= own a1)
                const float na2 = lae2(a2, a1) + lp0;

                a0 = na0; a1 = na1; a2 = na2;
            }
        }
        __syncthreads();                       // barrier #c+1 (matches producers)
    }

    if (lane == 63) {
        out[b] = -lae2(a1, a2);                // -logaddexp(alpha[128], alpha[127])
    }
}

extern "C" void kernel_launch(void* const* d_in, const int* in_sizes, int n_in,
                              void* d_out, int out_size, void* d_ws, size_t ws_size,
                              hipStream_t stream) {
    const int*   y_true = (const int*)d_in[0];
    const float* y_pred = (const float*)d_in[1];
    float*       out    = (float*)d_out;

    const int B = in_sizes[0] / L_;            // 512
    ctc_kernel<<<dim3(B), dim3(256), 0, stream>>>(y_true, y_pred, out);
}

// Round 4
// 360.005 us; speedup vs baseline: 1.1633x; 1.0189x over previous
//
#include <hip/hip_runtime.h>

// CTC batch cost (K.ctc_batch_cost semantics), B=512, T=512, C=256 (blank=255), L=64.
//
// R4: linear-domain alpha recurrence + register-staged producers + raw barriers.
//   wave 0 (consumer): alpha in LINEAR domain: na0=(a0+pa1)*p0, na1=(a1+a0+c3)*p1,
//     na2=(a2+a1)*p0 (8 VALU/step). Every 4 steps: DPP wave-max -> uniform 2^-e
//     rescale, accumulate e; loss = -(log(a1+a2) + sum_e*ln2). pa1 via DPP
//     wave_shr:1 (bound_ctrl fill 0 == "no predecessor" identity).
//     Uses __syncthreads (its vmcnt(0) drain is free: no outstanding vmem).
//   waves 1,2 (producers): 8 rows each per 16-step chunk. Rows loaded into
//     REGISTERS (global dwordx4, lead-2 double buffer), class gather done
//     in-register via __shfl (ds_bpermute), blank via readlane(f.w,63);
//     only the compact p(label_l)/p(blank) per step is ds_written to a
//     2-slot LDS ring. Raw s_barrier + explicit s_waitcnt lgkmcnt(0) so the
//     prefetch loads stay in flight across barriers (no vmcnt(0) drain).
// Barrier protocol: chunk k published before barrier #k, consumed after it.
// Consumer executes 32 __syncthreads; producers 1 + 31 raw barriers. Matched.

#define EPSF (1e-7f)

constexpr int T_   = 512;
constexpr int C_   = 256;
constexpr int L_   = 64;
constexpr int TCH  = 16;           // time steps per chunk
constexpr int NCH  = T_ / TCH;     // 32 chunks
constexpr int RPW  = TCH / 2;      // 8 rows per producer wave (2 producers)

// lane n gets lane n-1's value; lane 0 gets 0.0f (linear-domain identity).
__device__ __forceinline__ float wave_shr1(float x) {
    int r = __builtin_amdgcn_update_dpp(0, __float_as_int(x),
                                        0x138 /* wave_shr:1 */, 0xF, 0xF, true);
    return __int_as_float(r);
}

template <int CTRL>
__device__ __forceinline__ float dppmax(float x) {
    int t = __builtin_amdgcn_update_dpp(0, __float_as_int(x), CTRL, 0xF, 0xF, true);
    return fmaxf(x, __int_as_float(t));
}

// max over all 64 lanes of non-negative x, broadcast as a uniform value.
__device__ __forceinline__ float wave_max_u(float x) {
    x = dppmax<0x111>(x);          // row_shr:1
    x = dppmax<0x112>(x);          // row_shr:2
    x = dppmax<0x114>(x);          // row_shr:4
    x = dppmax<0x118>(x);          // row_shr:8
    x = dppmax<0x142>(x);          // row_bcast:15
    x = dppmax<0x143>(x);          // row_bcast:31
    return __int_as_float(__builtin_amdgcn_readlane(__float_as_int(x), 63));
}

__global__ __launch_bounds__(192, 1)
void ctc_kernel(const int* __restrict__ y_true,
                const float* __restrict__ y_pred,
                float* __restrict__ out) {
    __shared__ float pLs[2][TCH][64];   // p(label_lane)+eps per step, 8 KB
    __shared__ float pBs[2][TCH];       // p(blank)+eps per step

    const int b     = blockIdx.x;
    const int tid   = threadIdx.x;
    const int lane  = tid & 63;
    const int wid   = tid >> 6;         // 0 consumer, 1..2 producers
    const int blank = C_ - 1;

    const float* __restrict__ row = y_pred + (size_t)b * T_ * C_;
    const int q = y_true[b * L_ + lane];          // label class of lane

    if (wid != 0) {
        // ---------------- producers ----------------
        const int  srcl  = q >> 2;                // lane holding class q
        const int  rbase = (wid - 1) * RPW;
        const float4* src = (const float4*)row + lane;   // row[4*lane ..]

        float4 A[RPW], B[RPW];
        auto loadC = [&](int c, float4* buf) {
#pragma unroll
            for (int r = 0; r < RPW; ++r)
                buf[r] = src[(size_t)(c * TCH + rbase + r) * (C_ / 4)];
        };
        auto prod = [&](int slot, const float4* buf) {
#pragma unroll
            for (int r = 0; r < RPW; ++r) {
                const float4 f = buf[r];
                const float vx = __shfl(f.x, srcl, 64);
                const float vy = __shfl(f.y, srcl, 64);
                const float vz = __shfl(f.z, srcl, 64);
                const float vw = __shfl(f.w, srcl, 64);
                const float t0 = (q & 2) ? vz : vx;
                const float t1 = (q & 2) ? vw : vy;
                const float pe = (q & 1) ? t1 : t0;
                pLs[slot][rbase + r][lane] = pe + EPSF;
                const float pbv = __int_as_float(
                    __builtin_amdgcn_readlane(__float_as_int(f.w), 63));
                if (lane == 0) pBs[slot][rbase + r] = pbv + EPSF;
            }
        };

        loadC(0, A); loadC(1, B);
        prod(0, A);                     // waits (fine-grained) on A only
        loadC(2, A);
        __builtin_amdgcn_s_waitcnt(0xC07F);   // lgkmcnt(0) only
        __builtin_amdgcn_s_barrier();         // barrier #0: chunk 0 published

        for (int c = 0; c + 1 < NCH; c += 2) {
            prod(1, B);                            // chunk c+1 (odd -> slot 1)
            if (c + 3 < NCH) loadC(c + 3, B);
            __builtin_amdgcn_s_waitcnt(0xC07F);
            __builtin_amdgcn_s_barrier();          // barrier #(c+1)
            if (c + 2 < NCH) {
                prod(0, A);                        // chunk c+2 (even -> slot 0)
                if (c + 4 < NCH) loadC(c + 4, A);
                __builtin_amdgcn_s_waitcnt(0xC07F);
                __builtin_amdgcn_s_barrier();      // barrier #(c+2)
            }
        }
        return;
    }

    // ---------------- consumer (wave 0) ----------------
    const int  pidx  = (lane == 0) ? 0 : (lane - 1);
    const int  qp    = y_true[b * L_ + pidx];
    const bool skip1 = (q != blank) && (lane != 0) && (q != qp);
    // (lane 0's skip value is irrelevant: pa1 == 0 there.)

    float a0 = 0.0f, a1 = 0.0f, a2 = 0.0f;
    int   kexp = 0;

    auto renorm = [&]() {
        float m = wave_max_u(fmaxf(fmaxf(a0, a1), a2));
        m = fmaxf(m, 1e-35f);
        const int   e  = (__float_as_int(m) >> 23) - 127;
        const float sc = __int_as_float((127 - e) << 23);  // 2^-e
        a0 *= sc; a1 *= sc; a2 *= sc; kexp += e;
    };
    auto step = [&](float p0, float p1) {
        const float pa1 = wave_shr1(a1);          // alpha[2l-1] (0 on lane 0)
        const float na0 = (a0 + pa1) * p0;        // state 2l   (blank)
        const float c3  = skip1 ? pa1 : 0.0f;
        const float na1 = (a1 + a0 + c3) * p1;    // state 2l+1 (label)
        const float na2 = (a2 + a1) * p0;         // state 128  (final blank)
        a0 = na0; a1 = na1; a2 = na2;
    };

    // chunk 0 (slot 0), with t=0 init
    __syncthreads();
    {
        float pl[TCH], pb[TCH];
#pragma unroll
        for (int j = 0; j < TCH; ++j) { pl[j] = pLs[0][j][lane]; pb[j] = pBs[0][j]; }
        a0 = (lane == 0) ? pb[0] : 0.0f;          // alpha0[0] = p(blank)+eps
        a1 = (lane == 0) ? pl[0] : 0.0f;          // alpha0[1] = p(l1)+eps
        a2 = 0.0f;
#pragma unroll
        for (int j = 1; j < TCH; ++j) {
            step(pb[j], pl[j]);
            if ((j & 3) == 3) renorm();
        }
    }
    // chunks 1..31
    auto consume = [&](int slot) {
        float pl[TCH], pb[TCH];
#pragma unroll
        for (int j = 0; j < TCH; ++j) { pl[j] = pLs[slot][j][lane]; pb[j] = pBs[slot][j]; }
#pragma unroll
        for (int j = 0; j < TCH; ++j) {
            step(pb[j], pl[j]);
            if ((j & 3) == 3) renorm();
        }
    };
    __syncthreads(); consume(1);                  // chunk 1
    for (int c = 2; c < NCH; c += 2) {
        __syncthreads(); consume(0);              // even chunk
        __syncthreads(); consume(1);              // odd chunk
    }

    if (lane == 63) {
        // a1 = alpha[127]*2^-kexp, a2 = alpha[128]*2^-kexp
        out[b] = -(__logf(a1 + a2) + (float)kexp * 0.69314718055994531f);
    }
}

extern "C" void kernel_launch(void* const* d_in, const int* in_sizes, int n_in,
                              void* d_out, int out_size, void* d_ws, size_t ws_size,
                              hipStream_t stream) {
    const int*   y_true = (const int*)d_in[0];
    const float* y_pred = (const float*)d_in[1];
    float*       out    = (float*)d_out;

    const int B = in_sizes[0] / L_;               // 512
    ctc_kernel<<<dim3(B), dim3(192), 0, stream>>>(y_true, y_pred, out);
}